// Round 2
// baseline (1034.568 us; speedup 1.0000x reference)
//
#include <hip/hip_runtime.h>
#include <hip/hip_bf16.h>
#include <math.h>

typedef __hip_bfloat16 bf16;
typedef __attribute__((ext_vector_type(8))) short bf16x8;  // 8 bf16 = 4 VGPR
typedef __attribute__((ext_vector_type(4))) float f32x4;

#define AS1 __attribute__((address_space(1)))
#define AS3 __attribute__((address_space(3)))

static constexpr int BATCH = 2, S = 2048, D = 2048, H = 16, HD = 128;
static constexpr int M = BATCH * S;  // 4096 token rows
static constexpr float SCALE = 0.08838834764831845f;  // 1/sqrt(128)

__device__ __forceinline__ void gload_lds16(const void* g, void* l) {
  // async global->LDS, 16B per lane; LDS dest must be wave-uniform base + lane*16
  __builtin_amdgcn_global_load_lds((AS1 void*)g, (AS3 void*)l, 16, 0, 0);
}

__device__ __forceinline__ unsigned short f2bu(float f) {
  bf16 h = __float2bfloat16(f);
  return *reinterpret_cast<unsigned short*>(&h);
}

// ---------------- fp32 -> bf16 cast (float4 / ushort4 vectorized) ----------------
__global__ void cast_kernel(const float* __restrict__ in,
                            unsigned short* __restrict__ out, int n4) {
  int i = blockIdx.x * blockDim.x + threadIdx.x;
  int stride = gridDim.x * blockDim.x;
  for (; i < n4; i += stride) {
    float4 v = reinterpret_cast<const float4*>(in)[i];
    ushort4 o;
    o.x = f2bu(v.x); o.y = f2bu(v.y); o.z = f2bu(v.z); o.w = f2bu(v.w);
    reinterpret_cast<ushort4*>(out)[i] = o;
  }
}

// ---------------- RoPE cos/sin table: cs[s*64+j] = {cos,sin}(s*invfreq[j]) ----------------
__global__ void rope_tab_kernel(float2* __restrict__ cs) {
  int s = blockIdx.x, j = threadIdx.x;  // grid S, block 64
  double inv = exp(-(double)j * 0.14391156831212793);  // ln(10000)*2/128
  float ang = (float)s * (float)inv;                   // match ref's fp32 product
  double da = (double)ang;
  cs[s * 64 + j] = make_float2((float)cos(da), (float)sin(da));
}

// ---------------- GEMM C[m,n] = sum_k A[m,k]*B[n,k]  (both K-major, bf16) -------------
// 128x128 tile, BK=32, 4 waves each 64x64 (4x4 frags of mfma 16x16x32 bf16).
// EPI: 0 = RoPE epilogue -> bf16 out [M][D]
//      1 = transpose epilogue -> bf16 Vt [B][H][HD][S]
//      2 = fp32 store -> out [M][D]
template <int EPI>
__global__ __launch_bounds__(256, 2) void gemm_bt(const bf16* __restrict__ A,
                                                  const bf16* __restrict__ B,
                                                  void* __restrict__ outp,
                                                  const float2* __restrict__ cs) {
  constexpr int K = 2048;
  __shared__ bf16 smA[2][128 * 32];
  __shared__ bf16 smB[2][128 * 32];
  const int tid = threadIdx.x;
  const int l = tid & 63, w = tid >> 6;
  const int wm = w >> 1, wn = w & 1;
  const int bm = blockIdx.y, bn = blockIdx.x;
  const int lr = l & 15, lg = l >> 4;

  f32x4 acc[4][4] = {};

  auto stage = [&](bf16* dst, const bf16* src, int row0, int k0) {
    // 128x32 bf16 tile = 8KB = 256 threads * 2 * 16B, linear in LDS
    #pragma unroll
    for (int i = 0; i < 2; ++i) {
      int idx = tid + i * 256;
      int row = idx >> 2, seg = idx & 3;
      gload_lds16(src + (size_t)(row0 + row) * K + k0 + seg * 8, dst + idx * 8);
    }
  };

  stage(smA[0], A, bm * 128, 0);
  stage(smB[0], B, bn * 128, 0);
  asm volatile("s_waitcnt vmcnt(0)" ::: "memory");
  __syncthreads();

  for (int kt = 0; kt < K / 32; ++kt) {
    const int cur = kt & 1;
    if (kt + 1 < K / 32) {
      stage(smA[cur ^ 1], A, bm * 128, (kt + 1) * 32);
      stage(smB[cur ^ 1], B, bn * 128, (kt + 1) * 32);
    }
    bf16x8 af[4], bfr[4];
    #pragma unroll
    for (int fm = 0; fm < 4; ++fm)
      af[fm] = *reinterpret_cast<const bf16x8*>(
          &smA[cur][(wm * 64 + fm * 16 + lr) * 32 + lg * 8]);
    #pragma unroll
    for (int fn = 0; fn < 4; ++fn)
      bfr[fn] = *reinterpret_cast<const bf16x8*>(
          &smB[cur][(wn * 64 + fn * 16 + lr) * 32 + lg * 8]);
    #pragma unroll
    for (int fm = 0; fm < 4; ++fm)
      #pragma unroll
      for (int fn = 0; fn < 4; ++fn)
        acc[fm][fn] = __builtin_amdgcn_mfma_f32_16x16x32_bf16(af[fm], bfr[fn],
                                                              acc[fm][fn], 0, 0, 0);
    __syncthreads();  // drains vmcnt (staged tile ready) + lgkmcnt (reads done)
  }

  // C frag mapping: row = (lane>>4)*4 + r, col = lane&15 (verified m89/m91)
  const int row0 = bm * 128 + wm * 64 + lg * 4;
  const int col0 = bn * 128 + wn * 64 + lr;

  if constexpr (EPI == 0) {
    // RoPE: q'[2i]   = q[2i]  *cos(th_{2i})   - q[2i+1]*sin(th_{2i})
    //       q'[2i+1] = q[2i+1]*cos(th_{2i+1}) + q[2i]  *sin(th_{2i+1})
    // th_d = s * invfreq[d & 63]; pair partner lives in lane^1 (col = lane&15)
    bf16* o = reinterpret_cast<bf16*>(outp);
    #pragma unroll
    for (int fm = 0; fm < 4; ++fm) {
      #pragma unroll
      for (int fn = 0; fn < 4; ++fn) {
        const int col = col0 + fn * 16;
        const int j = col & 63;
        const bool odd = (col & 1);
        #pragma unroll
        for (int r = 0; r < 4; ++r) {
          float v = acc[fm][fn][r];
          float p = __shfl_xor(v, 1);  // same (fm,fn,r), col^1
          int row = row0 + fm * 16 + r;
          int s = row & (S - 1);
          float2 c = cs[s * 64 + j];
          float nv = v * c.x + (odd ? p : -p) * c.y;
          o[(size_t)row * D + col] = __float2bfloat16(nv);
        }
      }
    }
  } else if constexpr (EPI == 1) {
    // store V transposed: Vt[(b*16+h)*128 + d][s], 4 consecutive s per lane -> 8B store
    bf16* o = reinterpret_cast<bf16*>(outp);
    #pragma unroll
    for (int fm = 0; fm < 4; ++fm) {
      #pragma unroll
      for (int fn = 0; fn < 4; ++fn) {
        int row = row0 + fm * 16;  // r=0 row; rows row..row+3
        int col = col0 + fn * 16;
        int b_ = row >> 11, sp = row & (S - 1);
        int h = col >> 7, d = col & (HD - 1);
        size_t off = ((size_t)(b_ * H + h) * HD + d) * S + sp;
        ushort4 pk;
        pk.x = f2bu(acc[fm][fn][0]);
        pk.y = f2bu(acc[fm][fn][1]);
        pk.z = f2bu(acc[fm][fn][2]);
        pk.w = f2bu(acc[fm][fn][3]);
        *reinterpret_cast<ushort4*>(o + off) = pk;
      }
    }
  } else {
    float* o = reinterpret_cast<float*>(outp);
    #pragma unroll
    for (int fm = 0; fm < 4; ++fm)
      #pragma unroll
      for (int fn = 0; fn < 4; ++fn)
        #pragma unroll
        for (int r = 0; r < 4; ++r)
          o[(size_t)(row0 + fm * 16 + r) * D + col0 + fn * 16] = acc[fm][fn][r];
  }
}

// ---------------- flash attention ----------------
// grid (S/64, B*H), 256 threads = 4 waves; wave w owns q-rows [bx*64+w*16, +16)
// K,V read straight from global (per-head K/V = 512KB each, L2-resident).
__global__ __launch_bounds__(256, 2) void attn_kernel(const bf16* __restrict__ Q,
                                                      const bf16* __restrict__ Kmat,
                                                      const bf16* __restrict__ Vt,
                                                      bf16* __restrict__ O) {
  __shared__ bf16 plds[4][16][72];  // wave-private P transpose tile, +8 pad (2-way max)
  const int tid = threadIdx.x;
  const int l = tid & 63, w = tid >> 6;
  const int lr = l & 15, lg = l >> 4;
  const int bh = blockIdx.y;
  const int b = bh >> 4, h = bh & 15;
  const int q0 = blockIdx.x * 64 + w * 16;

  // Q A-frags (rows q0..q0+15, all 128 d): A row = lane&15, k = (lane>>4)*8+e
  bf16x8 aq[4];
  #pragma unroll
  for (int ks = 0; ks < 4; ++ks)
    aq[ks] = *reinterpret_cast<const bf16x8*>(
        &Q[((size_t)b * S + q0 + lr) * D + h * HD + ks * 32 + lg * 8]);

  f32x4 oacc[8] = {};
  float m[4], ls[4];
  #pragma unroll
  for (int r = 0; r < 4; ++r) { m[r] = -1e30f; ls[r] = 0.f; }

  for (int kv0 = 0; kv0 < S; kv0 += 64) {
    // ---- S tile = Q K^T : 16 q-rows x 64 kv ----
    f32x4 sf[4] = {};
    #pragma unroll
    for (int ksub = 0; ksub < 4; ++ksub) {
      #pragma unroll
      for (int ks = 0; ks < 4; ++ks) {
        bf16x8 bk = *reinterpret_cast<const bf16x8*>(
            &Kmat[((size_t)b * S + kv0 + ksub * 16 + lr) * D + h * HD + ks * 32 + lg * 8]);
        sf[ksub] = __builtin_amdgcn_mfma_f32_16x16x32_bf16(aq[ks], bk, sf[ksub], 0, 0, 0);
      }
    }
    // ---- online softmax (wave-parallel: 16-lane row groups) ----
    #pragma unroll
    for (int r = 0; r < 4; ++r) {
      float mx = fmaxf(fmaxf(sf[0][r], sf[1][r]), fmaxf(sf[2][r], sf[3][r]));
      #pragma unroll
      for (int off = 1; off < 16; off <<= 1) mx = fmaxf(mx, __shfl_xor(mx, off));
      float mn = fmaxf(m[r], mx * SCALE);
      float al = __expf(m[r] - mn);  // first tile: exp(-1e30) = 0
      m[r] = mn;
      ls[r] *= al;
      #pragma unroll
      for (int df = 0; df < 8; ++df) oacc[df][r] *= al;
      float psum = 0.f;
      #pragma unroll
      for (int ksub = 0; ksub < 4; ++ksub) {
        float p = __expf(sf[ksub][r] * SCALE - mn);
        psum += p;
        plds[w][lg * 4 + r][ksub * 16 + lr] = __float2bfloat16(p);
      }
      #pragma unroll
      for (int off = 1; off < 16; off <<= 1) psum += __shfl_xor(psum, off);
      ls[r] += psum;
    }
    // ---- P (A-frag via LDS transpose) x V ----
    bf16x8 pa0 = *reinterpret_cast<const bf16x8*>(&plds[w][lr][lg * 8]);
    bf16x8 pa1 = *reinterpret_cast<const bf16x8*>(&plds[w][lr][32 + lg * 8]);
    #pragma unroll
    for (int df = 0; df < 8; ++df) {
      const bf16* vrow = &Vt[((size_t)bh * HD + df * 16 + lr) * S + kv0];
      bf16x8 bv0 = *reinterpret_cast<const bf16x8*>(vrow + lg * 8);
      bf16x8 bv1 = *reinterpret_cast<const bf16x8*>(vrow + 32 + lg * 8);
      oacc[df] = __builtin_amdgcn_mfma_f32_16x16x32_bf16(pa0, bv0, oacc[df], 0, 0, 0);
      oacc[df] = __builtin_amdgcn_mfma_f32_16x16x32_bf16(pa1, bv1, oacc[df], 0, 0, 0);
    }
  }
  #pragma unroll
  for (int df = 0; df < 8; ++df) {
    #pragma unroll
    for (int r = 0; r < 4; ++r) {
      float v = oacc[df][r] / ls[r];
      O[((size_t)b * S + q0 + lg * 4 + r) * D + h * HD + df * 16 + lr] =
          __float2bfloat16(v);
    }
  }
}

extern "C" void kernel_launch(void* const* d_in, const int* in_sizes, int n_in,
                              void* d_out, int out_size, void* d_ws, size_t ws_size,
                              hipStream_t stream) {
  const float* hs = (const float*)d_in[0];
  const float* Wq = (const float*)d_in[1];
  const float* Wk = (const float*)d_in[2];
  const float* Wv = (const float*)d_in[3];
  const float* Wo = (const float*)d_in[4];
  // d_in[5] attention_mask: all-true -> ignored. d_in[6] position_ids = S.
  float* out = (float*)d_out;

  const size_t nTok = (size_t)M * D;  // 8.39M elems
  const size_t nW = (size_t)D * D;    // 4.19M elems
  bf16* hsb = (bf16*)d_ws;        // hs cast to bf16
  bf16* wqb = hsb + nTok;
  bf16* wkb = wqb + nW;
  bf16* wvb = wkb + nW;
  bf16* wob = wvb + nW;
  bf16* qb  = wob + nW;           // rope'd q  [M][D]
  bf16* kb  = qb + nTok;          // rope'd k  [M][D]
  bf16* vtb = kb + nTok;          // V transposed [B][H][HD][S]
  bf16* ob  = vtb + nTok;         // attention out [M][D]
  float2* cs = (float2*)(ob + nTok);  // rope table [S][64], 1MB

  cast_kernel<<<2048, 256, 0, stream>>>(hs, (unsigned short*)hsb, (int)(nTok / 4));
  cast_kernel<<<1024, 256, 0, stream>>>(Wq, (unsigned short*)wqb, (int)(nW / 4));
  cast_kernel<<<1024, 256, 0, stream>>>(Wk, (unsigned short*)wkb, (int)(nW / 4));
  cast_kernel<<<1024, 256, 0, stream>>>(Wv, (unsigned short*)wvb, (int)(nW / 4));
  cast_kernel<<<1024, 256, 0, stream>>>(Wo, (unsigned short*)wob, (int)(nW / 4));
  rope_tab_kernel<<<S, 64, 0, stream>>>(cs);

  dim3 gg(D / 128, M / 128);  // (16, 32)
  gemm_bt<0><<<gg, 256, 0, stream>>>(hsb, wqb, qb, cs);
  gemm_bt<0><<<gg, 256, 0, stream>>>(hsb, wkb, kb, cs);
  gemm_bt<1><<<gg, 256, 0, stream>>>(hsb, wvb, vtb, nullptr);

  attn_kernel<<<dim3(S / 64, BATCH * H), 256, 0, stream>>>(qb, kb, vtb, ob);

  gemm_bt<2><<<gg, 256, 0, stream>>>(ob, wob, out, nullptr);
}

// Round 3
// 515.489 us; speedup vs baseline: 2.0070x; 2.0070x over previous
//
#include <hip/hip_runtime.h>
#include <hip/hip_bf16.h>
#include <math.h>

typedef __hip_bfloat16 bf16;
typedef __attribute__((ext_vector_type(8))) short bf16x8;  // 8 bf16 = 4 VGPR
typedef __attribute__((ext_vector_type(4))) float f32x4;

#define AS1 __attribute__((address_space(1)))
#define AS3 __attribute__((address_space(3)))

static constexpr int BATCH = 2, S = 2048, D = 2048, H = 16, HD = 128;
static constexpr int M = BATCH * S;  // 4096 token rows
static constexpr float SCALE = 0.08838834764831845f;  // 1/sqrt(128)

__device__ __forceinline__ void gload_lds16(const void* g, void* l) {
  // async global->LDS, 16B per lane; LDS dest must be wave-uniform base + lane*16
  __builtin_amdgcn_global_load_lds((AS1 void*)g, (AS3 void*)l, 16, 0, 0);
}

__device__ __forceinline__ unsigned short f2bu(float f) {
  bf16 h = __float2bfloat16(f);
  return *reinterpret_cast<unsigned short*>(&h);
}

// ---------------- fp32 -> bf16 cast (float4 / ushort4 vectorized) ----------------
__global__ void cast_kernel(const float* __restrict__ in,
                            unsigned short* __restrict__ out, int n4) {
  int i = blockIdx.x * blockDim.x + threadIdx.x;
  int stride = gridDim.x * blockDim.x;
  for (; i < n4; i += stride) {
    float4 v = reinterpret_cast<const float4*>(in)[i];
    ushort4 o;
    o.x = f2bu(v.x); o.y = f2bu(v.y); o.z = f2bu(v.z); o.w = f2bu(v.w);
    reinterpret_cast<ushort4*>(out)[i] = o;
  }
}

// ---------------- RoPE cos/sin table: cs[s*64+j] = {cos,sin}(s*invfreq[j]) ----------------
__global__ void rope_tab_kernel(float2* __restrict__ cs) {
  int s = blockIdx.x, j = threadIdx.x;  // grid S, block 64
  double inv = exp(-(double)j * 0.14391156831212793);  // ln(10000)*2/128
  float ang = (float)s * (float)inv;                   // match ref's fp32 product
  double da = (double)ang;
  cs[s * 64 + j] = make_float2((float)cos(da), (float)sin(da));
}

// ---------------- GEMM C[m,n] = sum_k A[m,k]*B[n,k]  (both K-major, bf16) -------------
// 128x128 tile, BK=32, 4 waves each 64x64 (4x4 frags of mfma 16x16x32 bf16).
// EPI: 0 = RoPE epilogue -> bf16 out [M][D]
//      1 = transpose epilogue -> bf16 Vt [B][H][HD][S]
//      2 = fp32 store -> out [M][D]
template <int EPI>
__global__ __launch_bounds__(256, 2) void gemm_bt(const bf16* __restrict__ A,
                                                  const bf16* __restrict__ B,
                                                  void* __restrict__ outp,
                                                  const float2* __restrict__ cs) {
  constexpr int K = 2048;
  __shared__ bf16 smA[2][128 * 32];
  __shared__ bf16 smB[2][128 * 32];
  const int tid = threadIdx.x;
  const int l = tid & 63, w = tid >> 6;
  const int wm = w >> 1, wn = w & 1;
  const int bm = blockIdx.y, bn = blockIdx.x;
  const int lr = l & 15, lg = l >> 4;

  f32x4 acc[4][4] = {};

  auto stage = [&](bf16* dst, const bf16* src, int row0, int k0) {
    // 128x32 bf16 tile = 8KB = 256 threads * 2 * 16B, linear in LDS
    #pragma unroll
    for (int i = 0; i < 2; ++i) {
      int idx = tid + i * 256;
      int row = idx >> 2, seg = idx & 3;
      gload_lds16(src + (size_t)(row0 + row) * K + k0 + seg * 8, dst + idx * 8);
    }
  };

  stage(smA[0], A, bm * 128, 0);
  stage(smB[0], B, bn * 128, 0);
  asm volatile("s_waitcnt vmcnt(0)" ::: "memory");
  __syncthreads();

  for (int kt = 0; kt < K / 32; ++kt) {
    const int cur = kt & 1;
    if (kt + 1 < K / 32) {
      stage(smA[cur ^ 1], A, bm * 128, (kt + 1) * 32);
      stage(smB[cur ^ 1], B, bn * 128, (kt + 1) * 32);
    }
    bf16x8 af[4], bfr[4];
    #pragma unroll
    for (int fm = 0; fm < 4; ++fm)
      af[fm] = *reinterpret_cast<const bf16x8*>(
          &smA[cur][(wm * 64 + fm * 16 + lr) * 32 + lg * 8]);
    #pragma unroll
    for (int fn = 0; fn < 4; ++fn)
      bfr[fn] = *reinterpret_cast<const bf16x8*>(
          &smB[cur][(wn * 64 + fn * 16 + lr) * 32 + lg * 8]);
    #pragma unroll
    for (int fm = 0; fm < 4; ++fm)
      #pragma unroll
      for (int fn = 0; fn < 4; ++fn)
        acc[fm][fn] = __builtin_amdgcn_mfma_f32_16x16x32_bf16(af[fm], bfr[fn],
                                                              acc[fm][fn], 0, 0, 0);
    __syncthreads();  // drains vmcnt (staged tile ready) + lgkmcnt (reads done)
  }

  // C frag mapping: row = (lane>>4)*4 + r, col = lane&15 (verified m89/m91)
  const int row0 = bm * 128 + wm * 64 + lg * 4;
  const int col0 = bn * 128 + wn * 64 + lr;

  if constexpr (EPI == 0) {
    // RoPE: q'[2i]   = q[2i]  *cos(th_{2i})   - q[2i+1]*sin(th_{2i})
    //       q'[2i+1] = q[2i+1]*cos(th_{2i+1}) + q[2i]  *sin(th_{2i+1})
    // th_d = s * invfreq[d & 63]; pair partner lives in lane^1 (col = lane&15)
    bf16* o = reinterpret_cast<bf16*>(outp);
    #pragma unroll
    for (int fm = 0; fm < 4; ++fm) {
      #pragma unroll
      for (int fn = 0; fn < 4; ++fn) {
        const int col = col0 + fn * 16;
        const int j = col & 63;
        const bool odd = (col & 1);
        #pragma unroll
        for (int r = 0; r < 4; ++r) {
          float v = acc[fm][fn][r];
          float p = __shfl_xor(v, 1);  // same (fm,fn,r), col^1
          int row = row0 + fm * 16 + r;
          int s = row & (S - 1);
          float2 c = cs[s * 64 + j];
          float nv = v * c.x + (odd ? p : -p) * c.y;
          o[(size_t)row * D + col] = __float2bfloat16(nv);
        }
      }
    }
  } else if constexpr (EPI == 1) {
    // store V transposed: Vt[(b*16+h)*128 + d][s], 4 consecutive s per lane -> 8B store
    bf16* o = reinterpret_cast<bf16*>(outp);
    #pragma unroll
    for (int fm = 0; fm < 4; ++fm) {
      #pragma unroll
      for (int fn = 0; fn < 4; ++fn) {
        int row = row0 + fm * 16;  // r=0 row; rows row..row+3
        int col = col0 + fn * 16;
        int b_ = row >> 11, sp = row & (S - 1);
        int h = col >> 7, d = col & (HD - 1);
        size_t off = ((size_t)(b_ * H + h) * HD + d) * S + sp;
        ushort4 pk;
        pk.x = f2bu(acc[fm][fn][0]);
        pk.y = f2bu(acc[fm][fn][1]);
        pk.z = f2bu(acc[fm][fn][2]);
        pk.w = f2bu(acc[fm][fn][3]);
        *reinterpret_cast<ushort4*>(o + off) = pk;
      }
    }
  } else {
    float* o = reinterpret_cast<float*>(outp);
    #pragma unroll
    for (int fm = 0; fm < 4; ++fm)
      #pragma unroll
      for (int fn = 0; fn < 4; ++fn)
        #pragma unroll
        for (int r = 0; r < 4; ++r)
          o[(size_t)(row0 + fm * 16 + r) * D + col0 + fn * 16] = acc[fm][fn][r];
  }
}

// ---------------- flash attention ----------------
// grid (S/64, B*H), 256 threads = 4 waves; wave w owns q-rows [bx*64+w*16, +16)
// K (64x128) and V (128x64) tiles staged block-wide into LDS, double-buffered via
// global_load_lds (issue at loop top, drain at loop bottom -> latency hidden under
// QK+softmax+PV). XOR swizzle byte^=((row&7)<<4) on both stage-source and read
// (rule #21: linear LDS dest + inverse-swizzled global src + swizzled ds_read).
__global__ __launch_bounds__(256, 2) void attn_kernel(const bf16* __restrict__ Q,
                                                      const bf16* __restrict__ Kmat,
                                                      const bf16* __restrict__ Vt,
                                                      bf16* __restrict__ O) {
  __shared__ bf16 kv_lds[2][16384];  // [buf][ K 64x128 | V 128x64 ], 32KB each
  __shared__ bf16 plds[4][16][72];   // wave-private P transpose tile, +8 pad
  const int tid = threadIdx.x;
  const int l = tid & 63, w = tid >> 6;
  const int lr = l & 15, lg = l >> 4;
  const int bh = blockIdx.y;
  const int b = bh >> 4, h = bh & 15;
  const int q0 = blockIdx.x * 64 + w * 16;

  // Q A-frags (rows q0..q0+15, all 128 d): A row = lane&15, k = (lane>>4)*8+e
  bf16x8 aq[4];
  #pragma unroll
  for (int ks = 0; ks < 4; ++ks)
    aq[ks] = *reinterpret_cast<const bf16x8*>(
        &Q[((size_t)b * S + q0 + lr) * D + h * HD + ks * 32 + lg * 8]);

  // staging sources (per-thread 4 granules of 16B for K, 4 for V)
  // K tile: row 0..63 (16 granules/row), V tile: row 0..127 (8 granules/row)
  const bf16* ksrc[4];
  const bf16* vsrc[4];
  int kldsoff[4], vldsoff[4];
  #pragma unroll
  for (int i = 0; i < 4; ++i) {
    int idx = tid + i * 256;
    int krow = idx >> 4, kcb = (idx & 15) << 4;
    int kcol = (kcb ^ ((krow & 7) << 4)) >> 1;  // inverse-swizzled source col (elems)
    ksrc[i] = Kmat + ((size_t)b * S + krow) * D + h * HD + kcol;
    kldsoff[i] = idx * 8;  // elems; byte = idx*16, linear
    int vrow = idx >> 3, vcb = (idx & 7) << 4;
    int vcol = (vcb ^ ((vrow & 7) << 4)) >> 1;
    vsrc[i] = Vt + ((size_t)bh * HD + vrow) * S + vcol;
    vldsoff[i] = 8192 + idx * 8;
  }

  auto stage = [&](int buf, int t) {
    #pragma unroll
    for (int i = 0; i < 4; ++i) {
      gload_lds16(ksrc[i] + (size_t)t * 64 * D, &kv_lds[buf][kldsoff[i]]);
      gload_lds16(vsrc[i] + t * 64, &kv_lds[buf][vldsoff[i]]);
    }
  };

  f32x4 oacc[8] = {};
  float m[4], ls[4];
  #pragma unroll
  for (int r = 0; r < 4; ++r) { m[r] = -1e30f; ls[r] = 0.f; }

  stage(0, 0);
  asm volatile("s_waitcnt vmcnt(0)" ::: "memory");
  __syncthreads();

  const int swz = (lr & 7) << 4;  // read-side byte swizzle ((row&7)<<4, row%8==lr%8)

  for (int t = 0; t < S / 64; ++t) {
    const int cur = t & 1;
    if (t + 1 < S / 64) stage(cur ^ 1, t + 1);  // issue-early; drained at loop bottom
    const bf16* Kl = &kv_lds[cur][0];
    const bf16* Vl = &kv_lds[cur][8192];

    // ---- S tile = Q K^T : 16 q-rows x 64 kv ----
    f32x4 sf[4] = {};
    #pragma unroll
    for (int ksub = 0; ksub < 4; ++ksub) {
      #pragma unroll
      for (int ks = 0; ks < 4; ++ks) {
        bf16x8 bk = *reinterpret_cast<const bf16x8*>(
            &Kl[(ksub * 16 + lr) * 128 + (((ks * 64 + lg * 16) ^ swz) >> 1)]);
        sf[ksub] = __builtin_amdgcn_mfma_f32_16x16x32_bf16(aq[ks], bk, sf[ksub], 0, 0, 0);
      }
    }
    // ---- online softmax (wave-parallel: 16-lane row groups) ----
    #pragma unroll
    for (int r = 0; r < 4; ++r) {
      float mx = fmaxf(fmaxf(sf[0][r], sf[1][r]), fmaxf(sf[2][r], sf[3][r]));
      #pragma unroll
      for (int off = 1; off < 16; off <<= 1) mx = fmaxf(mx, __shfl_xor(mx, off));
      float mn = fmaxf(m[r], mx * SCALE);
      float al = __expf(m[r] - mn);  // first tile: exp(-1e30) = 0
      m[r] = mn;
      ls[r] *= al;
      #pragma unroll
      for (int df = 0; df < 8; ++df) oacc[df][r] *= al;
      float psum = 0.f;
      #pragma unroll
      for (int ksub = 0; ksub < 4; ++ksub) {
        float p = __expf(sf[ksub][r] * SCALE - mn);
        psum += p;
        plds[w][lg * 4 + r][ksub * 16 + lr] = __float2bfloat16(p);
      }
      #pragma unroll
      for (int off = 1; off < 16; off <<= 1) psum += __shfl_xor(psum, off);
      ls[r] += psum;
    }
    // ---- P (A-frag via LDS transpose) x V ----
    bf16x8 pa0 = *reinterpret_cast<const bf16x8*>(&plds[w][lr][lg * 8]);
    bf16x8 pa1 = *reinterpret_cast<const bf16x8*>(&plds[w][lr][32 + lg * 8]);
    #pragma unroll
    for (int df = 0; df < 8; ++df) {
      const int vr = df * 16 + lr;
      bf16x8 bv0 = *reinterpret_cast<const bf16x8*>(
          &Vl[vr * 64 + (((lg * 16) ^ swz) >> 1)]);
      bf16x8 bv1 = *reinterpret_cast<const bf16x8*>(
          &Vl[vr * 64 + (((64 + lg * 16) ^ swz) >> 1)]);
      oacc[df] = __builtin_amdgcn_mfma_f32_16x16x32_bf16(pa0, bv0, oacc[df], 0, 0, 0);
      oacc[df] = __builtin_amdgcn_mfma_f32_16x16x32_bf16(pa1, bv1, oacc[df], 0, 0, 0);
    }
    asm volatile("s_waitcnt vmcnt(0)" ::: "memory");
    __syncthreads();  // staged tile landed; all waves done reading cur
  }
  #pragma unroll
  for (int df = 0; df < 8; ++df) {
    #pragma unroll
    for (int r = 0; r < 4; ++r) {
      float v = oacc[df][r] / ls[r];
      O[((size_t)b * S + q0 + lg * 4 + r) * D + h * HD + df * 16 + lr] =
          __float2bfloat16(v);
    }
  }
}

extern "C" void kernel_launch(void* const* d_in, const int* in_sizes, int n_in,
                              void* d_out, int out_size, void* d_ws, size_t ws_size,
                              hipStream_t stream) {
  const float* hs = (const float*)d_in[0];
  const float* Wq = (const float*)d_in[1];
  const float* Wk = (const float*)d_in[2];
  const float* Wv = (const float*)d_in[3];
  const float* Wo = (const float*)d_in[4];
  // d_in[5] attention_mask: all-true -> ignored. d_in[6] position_ids = S.
  float* out = (float*)d_out;

  const size_t nTok = (size_t)M * D;  // 8.39M elems
  const size_t nW = (size_t)D * D;    // 4.19M elems
  bf16* hsb = (bf16*)d_ws;        // hs cast to bf16
  bf16* wqb = hsb + nTok;
  bf16* wkb = wqb + nW;
  bf16* wvb = wkb + nW;
  bf16* wob = wvb + nW;
  bf16* qb  = wob + nW;           // rope'd q  [M][D]
  bf16* kb  = qb + nTok;          // rope'd k  [M][D]
  bf16* vtb = kb + nTok;          // V transposed [B][H][HD][S]
  bf16* ob  = vtb + nTok;         // attention out [M][D]
  float2* cs = (float2*)(ob + nTok);  // rope table [S][64], 1MB

  cast_kernel<<<2048, 256, 0, stream>>>(hs, (unsigned short*)hsb, (int)(nTok / 4));
  cast_kernel<<<1024, 256, 0, stream>>>(Wq, (unsigned short*)wqb, (int)(nW / 4));
  cast_kernel<<<1024, 256, 0, stream>>>(Wk, (unsigned short*)wkb, (int)(nW / 4));
  cast_kernel<<<1024, 256, 0, stream>>>(Wv, (unsigned short*)wvb, (int)(nW / 4));
  cast_kernel<<<1024, 256, 0, stream>>>(Wo, (unsigned short*)wob, (int)(nW / 4));
  rope_tab_kernel<<<S, 64, 0, stream>>>(cs);

  dim3 gg(D / 128, M / 128);  // (16, 32)
  gemm_bt<0><<<gg, 256, 0, stream>>>(hsb, wqb, qb, cs);
  gemm_bt<0><<<gg, 256, 0, stream>>>(hsb, wkb, kb, cs);
  gemm_bt<1><<<gg, 256, 0, stream>>>(hsb, wvb, vtb, nullptr);

  attn_kernel<<<dim3(S / 64, BATCH * H), 256, 0, stream>>>(qb, kb, vtb, ob);

  gemm_bt<2><<<gg, 256, 0, stream>>>(ob, wob, out, nullptr);
}

// Round 6
// 499.396 us; speedup vs baseline: 2.0716x; 1.0322x over previous
//
#include <hip/hip_runtime.h>
#include <hip/hip_bf16.h>
#include <math.h>

typedef __hip_bfloat16 bf16;
typedef __attribute__((ext_vector_type(8))) short bf16x8;  // 8 bf16 = 4 VGPR
typedef __attribute__((ext_vector_type(4))) float f32x4;

#define AS1 __attribute__((address_space(1)))
#define AS3 __attribute__((address_space(3)))

static constexpr int BATCH = 2, S = 2048, D = 2048, H = 16, HD = 128;
static constexpr int M = BATCH * S;  // 4096 token rows
static constexpr float SCALE = 0.08838834764831845f;  // 1/sqrt(128)

__device__ __forceinline__ void gload_lds16(const void* g, void* l) {
  // async global->LDS, 16B per lane; LDS dest must be wave-uniform base + lane*16
  __builtin_amdgcn_global_load_lds((AS1 void*)g, (AS3 void*)l, 16, 0, 0);
}

__device__ __forceinline__ unsigned short f2bu(float f) {
  bf16 h = __float2bfloat16(f);
  return *reinterpret_cast<unsigned short*>(&h);
}

// ---------------- fp32 -> bf16 cast (float4 / ushort4 vectorized) ----------------
__global__ void cast_kernel(const float* __restrict__ in,
                            unsigned short* __restrict__ out, int n4) {
  int i = blockIdx.x * blockDim.x + threadIdx.x;
  int stride = gridDim.x * blockDim.x;
  for (; i < n4; i += stride) {
    float4 v = reinterpret_cast<const float4*>(in)[i];
    ushort4 o;
    o.x = f2bu(v.x); o.y = f2bu(v.y); o.z = f2bu(v.z); o.w = f2bu(v.w);
    reinterpret_cast<ushort4*>(out)[i] = o;
  }
}

// ---------------- RoPE cos/sin table: cs[s*64+j] = {cos,sin}(s*invfreq[j]) ----------------
__global__ void rope_tab_kernel(float2* __restrict__ cs) {
  int s = blockIdx.x, j = threadIdx.x;  // grid S, block 64
  double inv = exp(-(double)j * 0.14391156831212793);  // ln(10000)*2/128
  float ang = (float)s * (float)inv;                   // match ref's fp32 product
  double da = (double)ang;
  cs[s * 64 + j] = make_float2((float)cos(da), (float)sin(da));
}

// ---------------- GEMM C[m,n] = sum_k A[m,k]*B[n,k]  (both K-major, bf16) -------------
// 128x128 tile, BK=32, 4 waves each 64x64 (4x4 frags of mfma 16x16x32 bf16).
// EPI: 0 = RoPE epilogue (scaled by oscale) -> bf16 out [M][D]
//      1 = transpose epilogue -> bf16 Vt [B][H][HD][S]
//      2 = fp32 store -> out [M][D]
template <int EPI>
__global__ __launch_bounds__(256, 2) void gemm_bt(const bf16* __restrict__ A,
                                                  const bf16* __restrict__ B,
                                                  void* __restrict__ outp,
                                                  const float2* __restrict__ cs,
                                                  float oscale) {
  constexpr int K = 2048;
  __shared__ bf16 smA[2][128 * 32];
  __shared__ bf16 smB[2][128 * 32];
  const int tid = threadIdx.x;
  const int l = tid & 63, w = tid >> 6;
  const int wm = w >> 1, wn = w & 1;
  const int bm = blockIdx.y, bn = blockIdx.x;
  const int lr = l & 15, lg = l >> 4;

  f32x4 acc[4][4] = {};

  auto stage = [&](bf16* dst, const bf16* src, int row0, int k0) {
    // 128x32 bf16 tile = 8KB = 256 threads * 2 * 16B, linear in LDS
    #pragma unroll
    for (int i = 0; i < 2; ++i) {
      int idx = tid + i * 256;
      int row = idx >> 2, seg = idx & 3;
      gload_lds16(src + (size_t)(row0 + row) * K + k0 + seg * 8, dst + idx * 8);
    }
  };

  stage(smA[0], A, bm * 128, 0);
  stage(smB[0], B, bn * 128, 0);
  asm volatile("s_waitcnt vmcnt(0)" ::: "memory");
  __syncthreads();

  for (int kt = 0; kt < K / 32; ++kt) {
    const int cur = kt & 1;
    if (kt + 1 < K / 32) {
      stage(smA[cur ^ 1], A, bm * 128, (kt + 1) * 32);
      stage(smB[cur ^ 1], B, bn * 128, (kt + 1) * 32);
    }
    bf16x8 af[4], bfr[4];
    #pragma unroll
    for (int fm = 0; fm < 4; ++fm)
      af[fm] = *reinterpret_cast<const bf16x8*>(
          &smA[cur][(wm * 64 + fm * 16 + lr) * 32 + lg * 8]);
    #pragma unroll
    for (int fn = 0; fn < 4; ++fn)
      bfr[fn] = *reinterpret_cast<const bf16x8*>(
          &smB[cur][(wn * 64 + fn * 16 + lr) * 32 + lg * 8]);
    #pragma unroll
    for (int fm = 0; fm < 4; ++fm)
      #pragma unroll
      for (int fn = 0; fn < 4; ++fn)
        acc[fm][fn] = __builtin_amdgcn_mfma_f32_16x16x32_bf16(af[fm], bfr[fn],
                                                              acc[fm][fn], 0, 0, 0);
    __syncthreads();  // drains vmcnt (staged tile ready) + lgkmcnt (reads done)
  }

  // C frag mapping: row = (lane>>4)*4 + r, col = lane&15 (verified m89/m91)
  const int row0 = bm * 128 + wm * 64 + lg * 4;
  const int col0 = bn * 128 + wn * 64 + lr;

  if constexpr (EPI == 0) {
    // RoPE: q'[2i]   = q[2i]  *cos(th_{2i})   - q[2i+1]*sin(th_{2i})
    //       q'[2i+1] = q[2i+1]*cos(th_{2i+1}) + q[2i]  *sin(th_{2i+1})
    // th_d = s * invfreq[d & 63]; pair partner lives in lane^1 (col = lane&15)
    bf16* o = reinterpret_cast<bf16*>(outp);
    #pragma unroll
    for (int fm = 0; fm < 4; ++fm) {
      #pragma unroll
      for (int fn = 0; fn < 4; ++fn) {
        const int col = col0 + fn * 16;
        const int j = col & 63;
        const bool odd = (col & 1);
        #pragma unroll
        for (int r = 0; r < 4; ++r) {
          float v = acc[fm][fn][r];
          float p = __shfl_xor(v, 1);  // same (fm,fn,r), col^1
          int row = row0 + fm * 16 + r;
          int s = row & (S - 1);
          float2 c = cs[s * 64 + j];
          float nv = (v * c.x + (odd ? p : -p) * c.y) * oscale;
          o[(size_t)row * D + col] = __float2bfloat16(nv);
        }
      }
    }
  } else if constexpr (EPI == 1) {
    // store V transposed: Vt[(b*16+h)*128 + d][s], 4 consecutive s per lane -> 8B store
    bf16* o = reinterpret_cast<bf16*>(outp);
    #pragma unroll
    for (int fm = 0; fm < 4; ++fm) {
      #pragma unroll
      for (int fn = 0; fn < 4; ++fn) {
        int row = row0 + fm * 16;  // r=0 row; rows row..row+3
        int col = col0 + fn * 16;
        int b_ = row >> 11, sp = row & (S - 1);
        int h = col >> 7, d = col & (HD - 1);
        size_t off = ((size_t)(b_ * H + h) * HD + d) * S + sp;
        ushort4 pk;
        pk.x = f2bu(acc[fm][fn][0]);
        pk.y = f2bu(acc[fm][fn][1]);
        pk.z = f2bu(acc[fm][fn][2]);
        pk.w = f2bu(acc[fm][fn][3]);
        *reinterpret_cast<ushort4*>(o + off) = pk;
      }
    }
  } else {
    float* o = reinterpret_cast<float*>(outp);
    #pragma unroll
    for (int fm = 0; fm < 4; ++fm)
      #pragma unroll
      for (int fn = 0; fn < 4; ++fn)
        #pragma unroll
        for (int r = 0; r < 4; ++r)
          o[(size_t)(row0 + fm * 16 + r) * D + col0 + fn * 16] = acc[fm][fn][r];
  }
}

// ---------------- flash attention ----------------
// grid (S/64, B*H), 256 threads = 4 waves; wave w owns q-rows [bx*64+w*16, +16)
// K (64x128) / V (128x64) double-buffered in LDS via global_load_lds (XOR-swizzled
// source + reads, rule #21). Q pre-scaled by 1/sqrt(hd). Softmax: defer-max (T13,
// THR=8), per-lane partial ls reduced once at the end. P transposed through the
// round-3-VERIFIED padded LDS tile (scalar b16 writes + b128 reads); the
// ds_read_b64_tr_b16 path was implicated in the round-5 correctness failure and
// is reverted pending an isolated layout probe.
__global__ __launch_bounds__(256, 2) void attn_kernel(const bf16* __restrict__ Q,
                                                      const bf16* __restrict__ Kmat,
                                                      const bf16* __restrict__ Vt,
                                                      bf16* __restrict__ O) {
  __shared__ bf16 kv_lds[2][16384];  // [buf][ K 64x128 | V 128x64 ], 32KB each
  __shared__ bf16 plds[4][16][72];   // wave-private P [q][kv], +8 pad (verified r3)
  const int tid = threadIdx.x;
  const int l = tid & 63, w = tid >> 6;
  const int lr = l & 15, lg = l >> 4;
  const int bh = blockIdx.y;
  const int b = bh >> 4, h = bh & 15;
  const int q0 = blockIdx.x * 64 + w * 16;

  // Q A-frags (rows q0..q0+15, all 128 d): A row = lane&15, k = (lane>>4)*8+e
  bf16x8 aq[4];
  #pragma unroll
  for (int ks = 0; ks < 4; ++ks)
    aq[ks] = *reinterpret_cast<const bf16x8*>(
        &Q[((size_t)b * S + q0 + lr) * D + h * HD + ks * 32 + lg * 8]);

  // staging sources (per-thread 4 granules of 16B for K, 4 for V)
  const bf16* ksrc[4];
  const bf16* vsrc[4];
  int kldsoff[4], vldsoff[4];
  #pragma unroll
  for (int i = 0; i < 4; ++i) {
    int idx = tid + i * 256;
    int krow = idx >> 4, kcb = (idx & 15) << 4;
    int kcol = (kcb ^ ((krow & 7) << 4)) >> 1;  // inverse-swizzled source col (elems)
    ksrc[i] = Kmat + ((size_t)b * S + krow) * D + h * HD + kcol;
    kldsoff[i] = idx * 8;  // elems; byte = idx*16, linear
    int vrow = idx >> 3, vcb = (idx & 7) << 4;
    int vcol = (vcb ^ ((vrow & 7) << 4)) >> 1;
    vsrc[i] = Vt + ((size_t)bh * HD + vrow) * S + vcol;
    vldsoff[i] = 8192 + idx * 8;
  }

  auto stage = [&](int buf, int t) {
    #pragma unroll
    for (int i = 0; i < 4; ++i) {
      gload_lds16(ksrc[i] + (size_t)t * 64 * D, &kv_lds[buf][kldsoff[i]]);
      gload_lds16(vsrc[i] + t * 64, &kv_lds[buf][vldsoff[i]]);
    }
  };

  f32x4 oacc[8] = {};
  float m[4], ls[4];
  #pragma unroll
  for (int r = 0; r < 4; ++r) { m[r] = -1e30f; ls[r] = 0.f; }

  stage(0, 0);
  asm volatile("s_waitcnt vmcnt(0)" ::: "memory");
  __syncthreads();

  const int swz = (lr & 7) << 4;  // read-side byte swizzle (row&7)<<4

  for (int t = 0; t < S / 64; ++t) {
    const int cur = t & 1;
    if (t + 1 < S / 64) stage(cur ^ 1, t + 1);  // issue-early; drained at loop bottom
    const bf16* Kl = &kv_lds[cur][0];
    const bf16* Vl = &kv_lds[cur][8192];

    // ---- S tile = Q K^T (Q pre-scaled) : 16 q-rows x 64 kv ----
    f32x4 sf[4] = {};
    __builtin_amdgcn_s_setprio(1);
    #pragma unroll
    for (int ksub = 0; ksub < 4; ++ksub) {
      #pragma unroll
      for (int ks = 0; ks < 4; ++ks) {
        bf16x8 bk = *reinterpret_cast<const bf16x8*>(
            &Kl[(ksub * 16 + lr) * 128 + (((ks * 64 + lg * 16) ^ swz) >> 1)]);
        sf[ksub] = __builtin_amdgcn_mfma_f32_16x16x32_bf16(aq[ks], bk, sf[ksub], 0, 0, 0);
      }
    }
    __builtin_amdgcn_s_setprio(0);

    // ---- online softmax: defer-max (THR=8), lane-partial ls ----
    #pragma unroll
    for (int r = 0; r < 4; ++r) {
      float mx = fmaxf(fmaxf(sf[0][r], sf[1][r]), fmaxf(sf[2][r], sf[3][r]));
      #pragma unroll
      for (int off = 1; off < 16; off <<= 1) mx = fmaxf(mx, __shfl_xor(mx, off));
      if (!__all(mx <= m[r] + 8.f)) {  // wave-uniform rescale (rare after tile 0)
        float mn = fmaxf(m[r], mx);
        float al = __expf(m[r] - mn);  // first tile: exp(-1e30) = 0
        m[r] = mn;
        ls[r] *= al;
        #pragma unroll
        for (int df = 0; df < 8; ++df) oacc[df][r] *= al;
      }
      // P = exp(s - m) <= e^8; write into verified padded transpose tile
      #pragma unroll
      for (int ksub = 0; ksub < 4; ++ksub) {
        float p = __expf(sf[ksub][r] - m[r]);
        ls[r] += p;
        plds[w][lg * 4 + r][ksub * 16 + lr] = __float2bfloat16(p);
      }
    }

    // ---- P (A-frag via LDS transpose) x V ----
    bf16x8 pa0 = *reinterpret_cast<const bf16x8*>(&plds[w][lr][lg * 8]);
    bf16x8 pa1 = *reinterpret_cast<const bf16x8*>(&plds[w][lr][32 + lg * 8]);
    __builtin_amdgcn_s_setprio(1);
    #pragma unroll
    for (int df = 0; df < 8; ++df) {
      const int vr = df * 16 + lr;
      bf16x8 bv0 = *reinterpret_cast<const bf16x8*>(
          &Vl[vr * 64 + (((lg * 16) ^ swz) >> 1)]);
      bf16x8 bv1 = *reinterpret_cast<const bf16x8*>(
          &Vl[vr * 64 + (((64 + lg * 16) ^ swz) >> 1)]);
      oacc[df] = __builtin_amdgcn_mfma_f32_16x16x32_bf16(pa0, bv0, oacc[df], 0, 0, 0);
      oacc[df] = __builtin_amdgcn_mfma_f32_16x16x32_bf16(pa1, bv1, oacc[df], 0, 0, 0);
    }
    __builtin_amdgcn_s_setprio(0);
    asm volatile("s_waitcnt vmcnt(0)" ::: "memory");
    __syncthreads();  // staged tile landed; all waves done reading cur
  }

  // final ls reduce over the 16-lane q-group (lr axis)
  #pragma unroll
  for (int r = 0; r < 4; ++r) {
    #pragma unroll
    for (int off = 1; off < 16; off <<= 1) ls[r] += __shfl_xor(ls[r], off);
    ls[r] = 1.0f / ls[r];
  }
  #pragma unroll
  for (int df = 0; df < 8; ++df) {
    #pragma unroll
    for (int r = 0; r < 4; ++r) {
      float v = oacc[df][r] * ls[r];
      O[((size_t)b * S + q0 + lg * 4 + r) * D + h * HD + df * 16 + lr] =
          __float2bfloat16(v);
    }
  }
}

extern "C" void kernel_launch(void* const* d_in, const int* in_sizes, int n_in,
                              void* d_out, int out_size, void* d_ws, size_t ws_size,
                              hipStream_t stream) {
  const float* hs = (const float*)d_in[0];
  const float* Wq = (const float*)d_in[1];
  const float* Wk = (const float*)d_in[2];
  const float* Wv = (const float*)d_in[3];
  const float* Wo = (const float*)d_in[4];
  // d_in[5] attention_mask: all-true -> ignored. d_in[6] position_ids = S.
  float* out = (float*)d_out;

  const size_t nTok = (size_t)M * D;  // 8.39M elems
  const size_t nW = (size_t)D * D;    // 4.19M elems
  bf16* hsb = (bf16*)d_ws;        // hs cast to bf16
  bf16* wqb = hsb + nTok;
  bf16* wkb = wqb + nW;
  bf16* wvb = wkb + nW;
  bf16* wob = wvb + nW;
  bf16* qb  = wob + nW;           // rope'd q (pre-scaled)  [M][D]
  bf16* kb  = qb + nTok;          // rope'd k  [M][D]
  bf16* vtb = kb + nTok;          // V transposed [B][H][HD][S]
  bf16* ob  = vtb + nTok;         // attention out [M][D]
  float2* cs = (float2*)(ob + nTok);  // rope table [S][64], 1MB

  cast_kernel<<<2048, 256, 0, stream>>>(hs, (unsigned short*)hsb, (int)(nTok / 4));
  cast_kernel<<<1024, 256, 0, stream>>>(Wq, (unsigned short*)wqb, (int)(nW / 4));
  cast_kernel<<<1024, 256, 0, stream>>>(Wk, (unsigned short*)wkb, (int)(nW / 4));
  cast_kernel<<<1024, 256, 0, stream>>>(Wv, (unsigned short*)wvb, (int)(nW / 4));
  cast_kernel<<<1024, 256, 0, stream>>>(Wo, (unsigned short*)wob, (int)(nW / 4));
  rope_tab_kernel<<<S, 64, 0, stream>>>(cs);

  dim3 gg(D / 128, M / 128);  // (16, 32)
  gemm_bt<0><<<gg, 256, 0, stream>>>(hsb, wqb, qb, cs, SCALE);  // Q pre-scaled
  gemm_bt<0><<<gg, 256, 0, stream>>>(hsb, wkb, kb, cs, 1.0f);
  gemm_bt<1><<<gg, 256, 0, stream>>>(hsb, wvb, vtb, nullptr, 1.0f);

  attn_kernel<<<dim3(S / 64, BATCH * H), 256, 0, stream>>>(qb, kb, vtb, ob);

  gemm_bt<2><<<gg, 256, 0, stream>>>(ob, wob, out, nullptr, 1.0f);
}

// Round 8
// 440.012 us; speedup vs baseline: 2.3512x; 1.1350x over previous
//
#include <hip/hip_runtime.h>
#include <hip/hip_bf16.h>
#include <math.h>

typedef __hip_bfloat16 bf16;
typedef __attribute__((ext_vector_type(8))) short bf16x8;  // 8 bf16 = 4 VGPR
typedef __attribute__((ext_vector_type(4))) float f32x4;

#define AS1 __attribute__((address_space(1)))
#define AS3 __attribute__((address_space(3)))

static constexpr int BATCH = 2, S = 2048, D = 2048, H = 16, HD = 128;
static constexpr int M = BATCH * S;  // 4096 token rows
static constexpr float SCALE = 0.08838834764831845f;  // 1/sqrt(128)

__device__ __forceinline__ void gload_lds16(const void* g, void* l) {
  // async global->LDS, 16B per lane; LDS dest must be wave-uniform base + lane*16
  __builtin_amdgcn_global_load_lds((AS1 void*)g, (AS3 void*)l, 16, 0, 0);
}

__device__ __forceinline__ unsigned short f2bu(float f) {
  bf16 h = __float2bfloat16(f);
  return *reinterpret_cast<unsigned short*>(&h);
}

// ---------------- fp32 -> bf16 cast (float4 / ushort4 vectorized) ----------------
__global__ void cast_kernel(const float* __restrict__ in,
                            unsigned short* __restrict__ out, int n4) {
  int i = blockIdx.x * blockDim.x + threadIdx.x;
  int stride = gridDim.x * blockDim.x;
  for (; i < n4; i += stride) {
    float4 v = reinterpret_cast<const float4*>(in)[i];
    ushort4 o;
    o.x = f2bu(v.x); o.y = f2bu(v.y); o.z = f2bu(v.z); o.w = f2bu(v.w);
    reinterpret_cast<ushort4*>(out)[i] = o;
  }
}

// ---------------- RoPE cos/sin table: cs[s*64+j] = {cos,sin}(s*invfreq[j]) ----------------
__global__ void rope_tab_kernel(float2* __restrict__ cs) {
  int s = blockIdx.x, j = threadIdx.x;  // grid S, block 64
  double inv = exp(-(double)j * 0.14391156831212793);  // ln(10000)*2/128
  float ang = (float)s * (float)inv;                   // match ref's fp32 product
  double da = (double)ang;
  cs[s * 64 + j] = make_float2((float)cos(da), (float)sin(da));
}

// ---------------- GEMM C[m,n] = sum_k A[m,k]*B[n,k]  (both K-major, bf16) -------------
// 128x128 tile, BK=32, 4 waves each 64x64 (4x4 frags of mfma 16x16x32 bf16).
// EPI: 0 = RoPE epilogue (scaled by oscale) -> bf16 out [M][D]
//      1 = transpose epilogue -> bf16 Vt [B][H][HD][S]
//      2 = fp32 store -> out [M][D]
template <int EPI>
__global__ __launch_bounds__(256, 2) void gemm_bt(const bf16* __restrict__ A,
                                                  const bf16* __restrict__ B,
                                                  void* __restrict__ outp,
                                                  const float2* __restrict__ cs,
                                                  float oscale) {
  constexpr int K = 2048;
  __shared__ bf16 smA[2][128 * 32];
  __shared__ bf16 smB[2][128 * 32];
  const int tid = threadIdx.x;
  const int l = tid & 63, w = tid >> 6;
  const int wm = w >> 1, wn = w & 1;
  const int bm = blockIdx.y, bn = blockIdx.x;
  const int lr = l & 15, lg = l >> 4;

  f32x4 acc[4][4] = {};

  auto stage = [&](bf16* dst, const bf16* src, int row0, int k0) {
    // 128x32 bf16 tile = 8KB = 256 threads * 2 * 16B, linear in LDS
    #pragma unroll
    for (int i = 0; i < 2; ++i) {
      int idx = tid + i * 256;
      int row = idx >> 2, seg = idx & 3;
      gload_lds16(src + (size_t)(row0 + row) * K + k0 + seg * 8, dst + idx * 8);
    }
  };

  stage(smA[0], A, bm * 128, 0);
  stage(smB[0], B, bn * 128, 0);
  asm volatile("s_waitcnt vmcnt(0)" ::: "memory");
  __syncthreads();

  for (int kt = 0; kt < K / 32; ++kt) {
    const int cur = kt & 1;
    if (kt + 1 < K / 32) {
      stage(smA[cur ^ 1], A, bm * 128, (kt + 1) * 32);
      stage(smB[cur ^ 1], B, bn * 128, (kt + 1) * 32);
    }
    bf16x8 af[4], bfr[4];
    #pragma unroll
    for (int fm = 0; fm < 4; ++fm)
      af[fm] = *reinterpret_cast<const bf16x8*>(
          &smA[cur][(wm * 64 + fm * 16 + lr) * 32 + lg * 8]);
    #pragma unroll
    for (int fn = 0; fn < 4; ++fn)
      bfr[fn] = *reinterpret_cast<const bf16x8*>(
          &smB[cur][(wn * 64 + fn * 16 + lr) * 32 + lg * 8]);
    #pragma unroll
    for (int fm = 0; fm < 4; ++fm)
      #pragma unroll
      for (int fn = 0; fn < 4; ++fn)
        acc[fm][fn] = __builtin_amdgcn_mfma_f32_16x16x32_bf16(af[fm], bfr[fn],
                                                              acc[fm][fn], 0, 0, 0);
    __syncthreads();  // drains vmcnt (staged tile ready) + lgkmcnt (reads done)
  }

  // C frag mapping: row = (lane>>4)*4 + r, col = lane&15 (verified m89/m91)
  const int row0 = bm * 128 + wm * 64 + lg * 4;
  const int col0 = bn * 128 + wn * 64 + lr;

  if constexpr (EPI == 0) {
    // RoPE: q'[2i]   = q[2i]  *cos(th_{2i})   - q[2i+1]*sin(th_{2i})
    //       q'[2i+1] = q[2i+1]*cos(th_{2i+1}) + q[2i]  *sin(th_{2i+1})
    // th_d = s * invfreq[d & 63]; pair partner lives in lane^1 (col = lane&15)
    bf16* o = reinterpret_cast<bf16*>(outp);
    #pragma unroll
    for (int fm = 0; fm < 4; ++fm) {
      #pragma unroll
      for (int fn = 0; fn < 4; ++fn) {
        const int col = col0 + fn * 16;
        const int j = col & 63;
        const bool odd = (col & 1);
        #pragma unroll
        for (int r = 0; r < 4; ++r) {
          float v = acc[fm][fn][r];
          float p = __shfl_xor(v, 1);  // same (fm,fn,r), col^1
          int row = row0 + fm * 16 + r;
          int s = row & (S - 1);
          float2 c = cs[s * 64 + j];
          float nv = (v * c.x + (odd ? p : -p) * c.y) * oscale;
          o[(size_t)row * D + col] = __float2bfloat16(nv);
        }
      }
    }
  } else if constexpr (EPI == 1) {
    // store V transposed: Vt[(b*16+h)*128 + d][s], 4 consecutive s per lane -> 8B store
    bf16* o = reinterpret_cast<bf16*>(outp);
    #pragma unroll
    for (int fm = 0; fm < 4; ++fm) {
      #pragma unroll
      for (int fn = 0; fn < 4; ++fn) {
        int row = row0 + fm * 16;  // r=0 row; rows row..row+3
        int col = col0 + fn * 16;
        int b_ = row >> 11, sp = row & (S - 1);
        int h = col >> 7, d = col & (HD - 1);
        size_t off = ((size_t)(b_ * H + h) * HD + d) * S + sp;
        ushort4 pk;
        pk.x = f2bu(acc[fm][fn][0]);
        pk.y = f2bu(acc[fm][fn][1]);
        pk.z = f2bu(acc[fm][fn][2]);
        pk.w = f2bu(acc[fm][fn][3]);
        *reinterpret_cast<ushort4*>(o + off) = pk;
      }
    }
  } else {
    float* o = reinterpret_cast<float*>(outp);
    #pragma unroll
    for (int fm = 0; fm < 4; ++fm)
      #pragma unroll
      for (int fn = 0; fn < 4; ++fn)
        #pragma unroll
        for (int r = 0; r < 4; ++r)
          o[(size_t)(row0 + fm * 16 + r) * D + col0 + fn * 16] = acc[fm][fn][r];
  }
}

// ---------------- flash attention (v3: QBLK=32/wave, V single-buffer pipeline) --------
// grid (S/128, B*H), 256 threads = 4 waves; wave w owns q-rows [bx*128+w*32, +32)
// as 2 q-subtiles of 16. K double-buffered (2x16KB), V single-buffered (16KB):
// per tile issue V[t]+K[t+1], vmcnt(4)+s_barrier before PV (V landed, K in flight),
// vmcnt(0)+s_barrier at tile end. K/V LDS reads amortized over 2 q-subtiles (the
// LDS pipe was ~70% busy at QBLK=16 -> traffic/unit halves). Softmax: lane-local
// threshold check (no shuffles on common path), defer-max THR=8, deferred ls.
__global__ __launch_bounds__(256, 2) void attn_kernel(const bf16* __restrict__ Q,
                                                      const bf16* __restrict__ Kmat,
                                                      const bf16* __restrict__ Vt,
                                                      bf16* __restrict__ O) {
  __shared__ bf16 kv_lds[24576];   // K0 @0, K1 @8192, V @16384 (elems); 48KB
  __shared__ bf16 plds[4][32][72]; // wave-private P [q][kv], +8 pad; 18KB
  const int tid = threadIdx.x;
  const int l = tid & 63, w = tid >> 6;
  const int lr = l & 15, lg = l >> 4;
  const int bh = blockIdx.y;
  const int b = bh >> 4, h = bh & 15;
  const int q0 = blockIdx.x * 128 + w * 32;

  // Q A-frags for 2 q-subtiles: A row = lane&15, k = (lane>>4)*8+e
  bf16x8 aq[2][4];
  #pragma unroll
  for (int qs = 0; qs < 2; ++qs)
    #pragma unroll
    for (int ks = 0; ks < 4; ++ks)
      aq[qs][ks] = *reinterpret_cast<const bf16x8*>(
          &Q[((size_t)b * S + q0 + qs * 16 + lr) * D + h * HD + ks * 32 + lg * 8]);

  // staging sources (per-thread 4 granules of 16B for K, 4 for V), XOR-swizzled src
  const bf16* ksrc[4];
  const bf16* vsrc[4];
  int koff[4], voff[4];
  #pragma unroll
  for (int i = 0; i < 4; ++i) {
    int idx = tid + i * 256;
    int krow = idx >> 4, kcb = (idx & 15) << 4;
    int kcol = (kcb ^ ((krow & 7) << 4)) >> 1;  // inverse-swizzled source col (elems)
    ksrc[i] = Kmat + ((size_t)b * S + krow) * D + h * HD + kcol;
    koff[i] = idx * 8;
    int vrow = idx >> 3, vcb = (idx & 7) << 4;
    int vcol = (vcb ^ ((vrow & 7) << 4)) >> 1;
    vsrc[i] = Vt + ((size_t)bh * HD + vrow) * S + vcol;
    voff[i] = 16384 + idx * 8;
  }

  f32x4 oacc[2][8] = {};
  float m[2][4], ls[2][4];
  #pragma unroll
  for (int qs = 0; qs < 2; ++qs)
    #pragma unroll
    for (int r = 0; r < 4; ++r) { m[qs][r] = -1e30f; ls[qs][r] = 0.f; }

  // prologue: K[0] into buf0
  #pragma unroll
  for (int i = 0; i < 4; ++i) gload_lds16(ksrc[i], &kv_lds[koff[i]]);
  asm volatile("s_waitcnt vmcnt(0)" ::: "memory");
  __syncthreads();

  const int swz = (lr & 7) << 4;  // read-side byte swizzle (row&7)<<4

  for (int t = 0; t < S / 64; ++t) {
    const int cur = t & 1;
    // issue V[t] (oldest 4) then K[t+1] (t=31 issues a harmless dummy into buf0;
    // source stays inside d_ws, drained by loop-end vmcnt(0))
    #pragma unroll
    for (int i = 0; i < 4; ++i) gload_lds16(vsrc[i] + t * 64, &kv_lds[voff[i]]);
    #pragma unroll
    for (int i = 0; i < 4; ++i)
      gload_lds16(ksrc[i] + (size_t)(t + 1) * 64 * D,
                  &kv_lds[(cur ^ 1) * 8192 + koff[i]]);
    const bf16* Kl = &kv_lds[cur * 8192];
    const bf16* Vl = &kv_lds[16384];

    // ---- S tiles = Q K^T (Q pre-scaled): 2 x (16 q-rows x 64 kv), bk shared ----
    f32x4 sf[2][4] = {};
    __builtin_amdgcn_s_setprio(1);
    #pragma unroll
    for (int ksub = 0; ksub < 4; ++ksub) {
      bf16x8 bk[4];
      #pragma unroll
      for (int ks = 0; ks < 4; ++ks)
        bk[ks] = *reinterpret_cast<const bf16x8*>(
            &Kl[(ksub * 16 + lr) * 128 + (((ks * 64 + lg * 16) ^ swz) >> 1)]);
      #pragma unroll
      for (int qs = 0; qs < 2; ++qs)
        #pragma unroll
        for (int ks = 0; ks < 4; ++ks)
          sf[qs][ksub] =
              __builtin_amdgcn_mfma_f32_16x16x32_bf16(aq[qs][ks], bk[ks], sf[qs][ksub], 0, 0, 0);
    }
    __builtin_amdgcn_s_setprio(0);

    // ---- softmax: lane-local threshold check; full reduce only when triggered ----
    float lmx[2][4];
    int ok = 1;
    #pragma unroll
    for (int qs = 0; qs < 2; ++qs)
      #pragma unroll
      for (int r = 0; r < 4; ++r) {
        lmx[qs][r] = fmaxf(fmaxf(sf[qs][0][r], sf[qs][1][r]),
                           fmaxf(sf[qs][2][r], sf[qs][3][r]));
        ok &= (lmx[qs][r] <= m[qs][r] + 8.f);
      }
    if (!__all(ok)) {  // wave-uniform slow path (always at t=0)
      #pragma unroll
      for (int qs = 0; qs < 2; ++qs)
        #pragma unroll
        for (int r = 0; r < 4; ++r) {
          float mxf = lmx[qs][r];
          #pragma unroll
          for (int off = 1; off < 16; off <<= 1) mxf = fmaxf(mxf, __shfl_xor(mxf, off));
          float mn = fmaxf(m[qs][r], mxf);
          float al = __expf(m[qs][r] - mn);  // t=0: exp(-1e30) = 0
          m[qs][r] = mn;
          ls[qs][r] *= al;
          #pragma unroll
          for (int df = 0; df < 8; ++df) oacc[qs][df][r] *= al;
        }
    }
    // P = exp(s - m) <= e^8; write into padded transpose tile (verified path)
    #pragma unroll
    for (int qs = 0; qs < 2; ++qs)
      #pragma unroll
      for (int ksub = 0; ksub < 4; ++ksub)
        #pragma unroll
        for (int r = 0; r < 4; ++r) {
          float p = __expf(sf[qs][ksub][r] - m[qs][r]);
          ls[qs][r] += p;
          plds[w][qs * 16 + lg * 4 + r][ksub * 16 + lr] = __float2bfloat16(p);
        }

    // ---- V[t] ready: counted wait (K[t+1] stays in flight) + raw barrier ----
    asm volatile("s_waitcnt vmcnt(4)" ::: "memory");
    __builtin_amdgcn_s_barrier();

    // ---- P (A-frag via LDS transpose) x V, bv shared across q-subtiles ----
    bf16x8 pa[2][2];
    #pragma unroll
    for (int qs = 0; qs < 2; ++qs)
      #pragma unroll
      for (int hh = 0; hh < 2; ++hh)
        pa[qs][hh] = *reinterpret_cast<const bf16x8*>(
            &plds[w][qs * 16 + lr][hh * 32 + lg * 8]);
    __builtin_amdgcn_s_setprio(1);
    #pragma unroll
    for (int df = 0; df < 8; ++df) {
      const int vr = df * 16 + lr;
      bf16x8 bv0 = *reinterpret_cast<const bf16x8*>(
          &Vl[vr * 64 + (((lg * 16) ^ swz) >> 1)]);
      bf16x8 bv1 = *reinterpret_cast<const bf16x8*>(
          &Vl[vr * 64 + (((64 + lg * 16) ^ swz) >> 1)]);
      #pragma unroll
      for (int qs = 0; qs < 2; ++qs) {
        oacc[qs][df] = __builtin_amdgcn_mfma_f32_16x16x32_bf16(pa[qs][0], bv0, oacc[qs][df], 0, 0, 0);
        oacc[qs][df] = __builtin_amdgcn_mfma_f32_16x16x32_bf16(pa[qs][1], bv1, oacc[qs][df], 0, 0, 0);
      }
    }
    __builtin_amdgcn_s_setprio(0);

    // ---- tile end: drain K[t+1] (latency already hidden), block-wide sync ----
    asm volatile("s_waitcnt vmcnt(0)" ::: "memory");
    __builtin_amdgcn_s_barrier();
  }

  // final ls reduce over the 16-lane q-group (lr axis)
  #pragma unroll
  for (int qs = 0; qs < 2; ++qs)
    #pragma unroll
    for (int r = 0; r < 4; ++r) {
      #pragma unroll
      for (int off = 1; off < 16; off <<= 1) ls[qs][r] += __shfl_xor(ls[qs][r], off);
      ls[qs][r] = 1.0f / ls[qs][r];
    }
  #pragma unroll
  for (int qs = 0; qs < 2; ++qs)
    #pragma unroll
    for (int df = 0; df < 8; ++df)
      #pragma unroll
      for (int r = 0; r < 4; ++r) {
        float v = oacc[qs][df][r] * ls[qs][r];
        O[((size_t)b * S + q0 + qs * 16 + lg * 4 + r) * D + h * HD + df * 16 + lr] =
            __float2bfloat16(v);
      }
}

extern "C" void kernel_launch(void* const* d_in, const int* in_sizes, int n_in,
                              void* d_out, int out_size, void* d_ws, size_t ws_size,
                              hipStream_t stream) {
  const float* hs = (const float*)d_in[0];
  const float* Wq = (const float*)d_in[1];
  const float* Wk = (const float*)d_in[2];
  const float* Wv = (const float*)d_in[3];
  const float* Wo = (const float*)d_in[4];
  // d_in[5] attention_mask: all-true -> ignored. d_in[6] position_ids = S.
  float* out = (float*)d_out;

  const size_t nTok = (size_t)M * D;  // 8.39M elems
  const size_t nW = (size_t)D * D;    // 4.19M elems
  bf16* hsb = (bf16*)d_ws;        // hs cast to bf16
  bf16* wqb = hsb + nTok;
  bf16* wkb = wqb + nW;
  bf16* wvb = wkb + nW;
  bf16* wob = wvb + nW;
  bf16* qb  = wob + nW;           // rope'd q (pre-scaled)  [M][D]
  bf16* kb  = qb + nTok;          // rope'd k  [M][D]
  bf16* vtb = kb + nTok;          // V transposed [B][H][HD][S]
  bf16* ob  = vtb + nTok;         // attention out [M][D]
  float2* cs = (float2*)(ob + nTok);  // rope table [S][64], 1MB

  cast_kernel<<<2048, 256, 0, stream>>>(hs, (unsigned short*)hsb, (int)(nTok / 4));
  cast_kernel<<<1024, 256, 0, stream>>>(Wq, (unsigned short*)wqb, (int)(nW / 4));
  cast_kernel<<<1024, 256, 0, stream>>>(Wk, (unsigned short*)wkb, (int)(nW / 4));
  cast_kernel<<<1024, 256, 0, stream>>>(Wv, (unsigned short*)wvb, (int)(nW / 4));
  cast_kernel<<<1024, 256, 0, stream>>>(Wo, (unsigned short*)wob, (int)(nW / 4));
  rope_tab_kernel<<<S, 64, 0, stream>>>(cs);

  dim3 gg(D / 128, M / 128);  // (16, 32)
  gemm_bt<0><<<gg, 256, 0, stream>>>(hsb, wqb, qb, cs, SCALE);  // Q pre-scaled
  gemm_bt<0><<<gg, 256, 0, stream>>>(hsb, wkb, kb, cs, 1.0f);
  gemm_bt<1><<<gg, 256, 0, stream>>>(hsb, wvb, vtb, nullptr, 1.0f);

  attn_kernel<<<dim3(S / 128, BATCH * H), 256, 0, stream>>>(qb, kb, vtb, ob);

  gemm_bt<2><<<gg, 256, 0, stream>>>(ob, wob, out, nullptr, 1.0f);
}